// Round 11
// baseline (131.605 us; speedup 1.0000x reference)
//
#include <hip/hip_runtime.h>
#include <math.h>

typedef unsigned short u16;
typedef unsigned int u32;
typedef short s8b __attribute__((ext_vector_type(8)));     // 8 x bf16 (raw shorts)
typedef float f4 __attribute__((ext_vector_type(4)));
typedef float f16v __attribute__((ext_vector_type(16)));
typedef unsigned short u16x4 __attribute__((ext_vector_type(4)));
typedef unsigned int u32x4 __attribute__((ext_vector_type(4)));
typedef float f32x4 __attribute__((ext_vector_type(4)));

// fold 1/sqrt(64) * log2(e) into Q so softmax uses exp2 directly
#define SCALE_Q 0.18033688011112042f

__device__ __forceinline__ u16 f2bf(float f) {
  u32 u = __builtin_bit_cast(u32, f);
  u += 0x7fffu + ((u >> 16) & 1u);   // RNE
  return (u16)(u >> 16);
}

// async global->LDS, 16B per lane
__device__ __forceinline__ void gl_lds16(const void* g, void* l) {
  __builtin_amdgcn_global_load_lds(
      (const __attribute__((address_space(1))) u32*)g,
      (__attribute__((address_space(3))) u32*)l, 16, 0, 0);
}

__device__ __forceinline__ u32 cvtpk_bf16(float lo, float hi) {
  u32 r;
  asm volatile("v_cvt_pk_bf16_f32 %0, %1, %2" : "=v"(r) : "v"(lo), "v"(hi));
  return r;
}

__device__ __forceinline__ void plswap(u32& a, u32& b) {
  asm volatile("v_permlane32_swap_b32 %0, %1" : "+v"(a), "+v"(b));
}

// ---------------------------------------------------------------- convert (weights only)
__global__ __launch_bounds__(256) void cvt_w(
    const float* __restrict__ wq, const float* __restrict__ wk,
    const float* __restrict__ wv, const float* __restrict__ wo,
    u16* __restrict__ wqo, u16* __restrict__ wko,
    u16* __restrict__ wvo, u16* __restrict__ woo)
{
  const int WQ4 = 147456;   // quads per weight
  const int TOT = 4 * WQ4;
  int i = blockIdx.x * 256 + threadIdx.x;
  const int stride = gridDim.x * 256;
  for (; i < TOT; i += stride) {
    int w = i / WQ4, off = i - w * WQ4;
    const float* s = (w == 0) ? wq : (w == 1) ? wk : (w == 2) ? wv : wo;
    u16* d = (w == 0) ? wqo : (w == 1) ? wko : (w == 2) ? wvo : woo;
    f32x4 v = ((const f32x4*)s)[off];
    u16x4 o = { f2bf(v[0]), f2bf(v[1]), f2bf(v[2]), f2bf(v[3]) };
    ((u16x4*)d)[off] = o;
  }
}

// ---------------------------------------------------------------- QKV GEMM
// (unchanged from round 8)
__global__ __launch_bounds__(256) void qkv_gemm(
    const float* __restrict__ X, const u16* __restrict__ Wq,
    const u16* __restrict__ Wk, const u16* __restrict__ Wv,
    u16* __restrict__ Qf, u16* __restrict__ Kf, u16* __restrict__ Vf)
{
  __shared__ float Af[2][128][32];    // f32 A tile (32KB)
  __shared__ u16  Bt[2][96][32];      // bf16 B tile (12KB)
  const int lane = threadIdx.x & 63;
  const int w    = threadIdx.x >> 6;
  const int wr = w >> 1, wc = w & 1;
  const int mb = blockIdx.x * 128;
  const int nb = blockIdx.y * 96;
  const int z  = blockIdx.z;
  const u16* W = (z == 0) ? Wq : (z == 1) ? Wk : Wv;

  const int lr = lane & 15;
  const int cl = lane >> 4;             // k-chunk 0..3

  const int srowB = lane >> 2;          // 0..15
  const int sxB = (lane & 3) ^ (srowB & 3);
  const int srowA = lane >> 3;          // 0..7
  const int cA = ((lane & 7) >> 1) ^ (srowA & 3);  // inverse-swizzled 32B chunk
  const int hA = lane & 1;              // 16B half

  const f4 fz = {0.f, 0.f, 0.f, 0.f};
  f4 acc[4][3];
#pragma unroll
  for (int i = 0; i < 4; ++i)
#pragma unroll
    for (int j = 0; j < 3; ++j) acc[i][j] = fz;

  const float* a0 = X + (size_t)mb * 768;
  const u16*   b0 = W + (size_t)nb * 768;

#define QKV_STAGE(d, k0)                                                        \
  {                                                                             \
    _Pragma("unroll")                                                           \
    for (int s = 0; s < 4; ++s) {                                               \
      const int r0 = w * 32 + s * 8;                                            \
      gl_lds16(a0 + (size_t)(r0 + srowA) * 768 + (k0) + cA * 8 + hA * 4,        \
               &Af[d][r0][0]);                                                  \
    }                                                                           \
    if (w < 3) {                                                                \
      gl_lds16(b0 + (size_t)(w * 32 + srowB) * 768 + (k0) + sxB * 8,            \
               &Bt[d][w * 32][0]);                                              \
      gl_lds16(b0 + (size_t)(w * 32 + 16 + srowB) * 768 + (k0) + sxB * 8,       \
               &Bt[d][w * 32 + 16][0]);                                         \
    }                                                                           \
  }

  QKV_STAGE(0, 0);
  __syncthreads();
  int db = 0;
  for (int t = 0; t < 24; ++t) {
    if (t < 23) QKV_STAGE(db ^ 1, (t + 1) * 32);
    s8b af[4], bf[3];
#pragma unroll
    for (int i = 0; i < 4; ++i) {
      const int rr = wr * 64 + i * 16 + lr;
      const float* ap = &Af[db][rr][(cl ^ (rr & 3)) * 8];
      f32x4 lo = *(const f32x4*)ap;
      f32x4 hi = *(const f32x4*)(ap + 4);
      u32x4 pk = { cvtpk_bf16(lo[0], lo[1]), cvtpk_bf16(lo[2], lo[3]),
                   cvtpk_bf16(hi[0], hi[1]), cvtpk_bf16(hi[2], hi[3]) };
      af[i] = __builtin_bit_cast(s8b, pk);
    }
#pragma unroll
    for (int j = 0; j < 3; ++j) {
      const int rr = wc * 48 + j * 16 + lr;
      bf[j] = *(const s8b*)&Bt[db][rr][(cl ^ (rr & 3)) * 8];
    }
#pragma unroll
    for (int i = 0; i < 4; ++i)
#pragma unroll
      for (int j = 0; j < 3; ++j)
        acc[i][j] = __builtin_amdgcn_mfma_f32_16x16x32_bf16(af[i], bf[j], acc[i][j], 0, 0, 0);
    __syncthreads();
    db ^= 1;
  }

  const int mbase = mb + wr * 64;
  const int nbase = nb + wc * 48;
  const int orow = cl * 4;
  if (z == 2) {
    // V fragment-major
#pragma unroll
    for (int i = 0; i < 4; ++i) {
      const int m0 = mbase + i * 16 + orow;   // kv token row
      const int b  = m0 >> 11, s0 = m0 & 2047;
      const int g16 = s0 >> 4, hi8 = (s0 >> 3) & 1, e0 = s0 & 7;
#pragma unroll
      for (int j = 0; j < 3; ++j) {
        const int n = nbase + j * 16 + lr;
        const int h = n >> 6, d6 = n & 63;
        const int dh = d6 >> 5, l31v = d6 & 31;
        u16x4 pk = { f2bf(acc[i][j][0]), f2bf(acc[i][j][1]),
                     f2bf(acc[i][j][2]), f2bf(acc[i][j][3]) };
        u16* dst = Vf + ((((size_t)(b * 12 + h) * 128 + g16) * 2 + dh) * 64
                         + hi8 * 32 + l31v) * 8 + e0;
        *(u16x4*)dst = pk;
      }
    }
  } else {
    // Q/K fragment-major
    u16* O = (z == 0) ? Qf : Kf;
    const float sc = (z == 0) ? SCALE_Q : 1.0f;
#pragma unroll
    for (int i = 0; i < 4; ++i) {
      const int m0 = mbase + i * 16 + orow;   // token row
      const int b  = m0 >> 11, s0 = m0 & 2047;
      const int g32 = s0 >> 5;
#pragma unroll
      for (int j = 0; j < 3; ++j) {
        const int n = nbase + j * 16 + lr;
        const int h = n >> 6, k6 = n & 63;
        const int ks = k6 >> 4, hi8 = (k6 >> 3) & 1, e = k6 & 7;
        u16* dst = O + ((((size_t)(b * 12 + h) * 64 + g32) * 4 + ks) * 64
                        + hi8 * 32) * 8 + e;
#pragma unroll
        for (int r = 0; r < 4; ++r)
          dst[(size_t)((s0 & 31) + r) * 8] = f2bf(acc[i][j][r] * sc);
      }
    }
  }
}

// ---------------------------------------------------------------- attention
// r8 structure + 2-DEEP K/V prefetch: named register sets A/B; body(t)
// computes from one set and immediately reloads it with tile t+2 (issue-to-
// use distance ~1.5 bodies covers L2/L3 latency). 1 wave/block, no LDS,
// no barriers, fragment-major loads, grid 1536, balanced pairing.
__global__ __launch_bounds__(64, 2) void attn_kernel(
    const u16* __restrict__ Qf, const u16* __restrict__ Kf,
    const u16* __restrict__ Vf, u16* __restrict__ Ctx)
{
  const int lane = threadIdx.x;
  const int idx = blockIdx.x;
  const int half = (idx >= 768) ? 1 : 0;
  const int base = idx - half * 768;
  const int bh = base % 24;
  const int m  = base / 24;                 // 0..31
  const int qt32 = half ? (2 * m) : (63 - 2 * m);
  const int bb = bh / 12, hh = bh % 12;
  const int qw0 = qt32 * 32;
  const int l31 = lane & 31;
  const int hi  = lane >> 5;

  const u16* qfp = Qf + ((size_t)bh * 64 + qt32) * 4 * 512;
  const u16* kfp = Kf + (size_t)bh * 64 * 4 * 512;
  const u16* vfp = Vf + (size_t)bh * 128 * 2 * 512;
  const int loff = lane * 8;

  s8b qf[4];
#pragma unroll
  for (int ks = 0; ks < 4; ++ks)
    qf[ks] = *(const s8b*)(qfp + ks * 512 + loff);

  s8b onesf;
#pragma unroll
  for (int i = 0; i < 8; ++i) onesf[i] = (short)0x3F80;   // bf16 1.0

  const f16v z16 = {0.f,0.f,0.f,0.f,0.f,0.f,0.f,0.f,
                    0.f,0.f,0.f,0.f,0.f,0.f,0.f,0.f};
  f16v oac0 = z16, oac1 = z16, lacc = z16;

  const int NT = qt32 >> 1;          // last kv-tile index
  const bool evenq = !(qt32 & 1);

  s8b kfA[8], vlA[4], vhA[4];
  s8b kfB[8], vlB[4], vhB[4];

#define LOADK(DST, T)                                                          \
  {                                                                            \
    _Pragma("unroll")                                                          \
    for (int mt = 0; mt < 2; ++mt)                                             \
      _Pragma("unroll")                                                        \
      for (int ks = 0; ks < 4; ++ks)                                           \
        DST[mt * 4 + ks] =                                                     \
            *(const s8b*)(kfp + ((size_t)(2 * (T) + mt) * 4 + ks) * 512 + loff); \
  }
#define LOADV(DL, DH, T)                                                       \
  {                                                                            \
    _Pragma("unroll")                                                          \
    for (int mt = 0; mt < 2; ++mt)                                             \
      _Pragma("unroll")                                                        \
      for (int k2 = 0; k2 < 2; ++k2) {                                         \
        const int g16_ = 4 * (T) + 2 * mt + k2;                                \
        DL[mt * 2 + k2] = *(const s8b*)(vfp + ((size_t)g16_ * 2 + 0) * 512 + loff); \
        DH[mt * 2 + k2] = *(const s8b*)(vfp + ((size_t)g16_ * 2 + 1) * 512 + loff); \
      }                                                                        \
  }

  LOADK(kfA, 0);
  LOADV(vlA, vhA, 0);
  if (NT >= 1) {
    LOADK(kfB, 1);
    LOADV(vlB, vhB, 1);
  }

  int t = 0;
#define ABODY(KF, VL, VH)                                                      \
  {                                                                            \
    const bool last_ = (t == NT);                                              \
    const bool do1_ = !(last_ && evenq);                                       \
    f16v st0 = z16, st1 = z16;                                                 \
    __builtin_amdgcn_s_setprio(1);                                             \
    _Pragma("unroll")                                                          \
    for (int ks = 0; ks < 4; ++ks)                                             \
      st0 = __builtin_amdgcn_mfma_f32_32x32x16_bf16(KF[ks], qf[ks], st0, 0, 0, 0); \
    if (do1_) {                                                                \
      _Pragma("unroll")                                                        \
      for (int ks = 0; ks < 4; ++ks)                                           \
        st1 = __builtin_amdgcn_mfma_f32_32x32x16_bf16(KF[4 + ks], qf[ks], st1, 0, 0, 0); \
    }                                                                          \
    __builtin_amdgcn_s_setprio(0);                                             \
    if (t + 2 <= NT) LOADK(KF, t + 2);                                         \
    float p0[16], p1[16];                                                      \
    if (last_) {                                                               \
      if (evenq) {                                                             \
        _Pragma("unroll")                                                      \
        for (int r = 0; r < 16; ++r) {                                         \
          const int crow = (r & 3) + 8 * (r >> 2) + 4 * hi;                    \
          p0[r] = (crow <= l31) ? exp2f(st0[r]) : 0.f;                         \
        }                                                                      \
      } else {                                                                 \
        _Pragma("unroll")                                                      \
        for (int r = 0; r < 16; ++r) p0[r] = exp2f(st0[r]);                    \
        _Pragma("unroll")                                                      \
        for (int r = 0; r < 16; ++r) {                                         \
          const int crow = (r & 3) + 8 * (r >> 2) + 4 * hi;                    \
          p1[r] = (crow <= l31) ? exp2f(st1[r]) : 0.f;                         \
        }                                                                      \
      }                                                                        \
    } else {                                                                   \
      _Pragma("unroll")                                                        \
      for (int r = 0; r < 16; ++r) p0[r] = exp2f(st0[r]);                      \
      _Pragma("unroll")                                                        \
      for (int r = 0; r < 16; ++r) p1[r] = exp2f(st1[r]);                      \
    }                                                                          \
    _Pragma("unroll")                                                          \
    for (int mt = 0; mt < 2; ++mt) {                                           \
      if (mt == 1 && !do1_) break;                                             \
      const float* pp = (mt == 0) ? p0 : p1;                                   \
      u32 pk0 = cvtpk_bf16(pp[0],  pp[1]);                                     \
      u32 pk1 = cvtpk_bf16(pp[2],  pp[3]);                                     \
      u32 pk2 = cvtpk_bf16(pp[4],  pp[5]);                                     \
      u32 pk3 = cvtpk_bf16(pp[6],  pp[7]);                                     \
      u32 pk4 = cvtpk_bf16(pp[8],  pp[9]);                                     \
      u32 pk5 = cvtpk_bf16(pp[10], pp[11]);                                    \
      u32 pk6 = cvtpk_bf16(pp[12], pp[13]);                                    \
      u32 pk7 = cvtpk_bf16(pp[14], pp[15]);                                    \
      plswap(pk0, pk2);                                                        \
      plswap(pk1, pk3);                                                        \
      plswap(pk4, pk6);                                                        \
      plswap(pk5, pk7);                                                        \
      u32x4 w0_ = { pk0, pk1, pk2, pk3 };                                      \
      u32x4 w1_ = { pk4, pk5, pk6, pk7 };                                      \
      s8b pa0 = __builtin_bit_cast(s8b, w0_);                                  \
      s8b pa1 = __builtin_bit_cast(s8b, w1_);                                  \
      __builtin_amdgcn_s_setprio(1);                                           \
      oac0 = __builtin_amdgcn_mfma_f32_32x32x16_bf16(pa0, VL[mt * 2 + 0], oac0, 0, 0, 0); \
      oac0 = __builtin_amdgcn_mfma_f32_32x32x16_bf16(pa1, VL[mt * 2 + 1], oac0, 0, 0, 0); \
      oac1 = __builtin_amdgcn_mfma_f32_32x32x16_bf16(pa0, VH[mt * 2 + 0], oac1, 0, 0, 0); \
      oac1 = __builtin_amdgcn_mfma_f32_32x32x16_bf16(pa1, VH[mt * 2 + 1], oac1, 0, 0, 0); \
      lacc = __builtin_amdgcn_mfma_f32_32x32x16_bf16(pa0, onesf, lacc, 0, 0, 0);          \
      lacc = __builtin_amdgcn_mfma_f32_32x32x16_bf16(pa1, onesf, lacc, 0, 0, 0);          \
      __builtin_amdgcn_s_setprio(0);                                           \
    }                                                                          \
    if (t + 2 <= NT) LOADV(VL, VH, t + 2);                                     \
    ++t;                                                                       \
  }

  while (1) {
    ABODY(kfA, vlA, vhA);
    if (t > NT) break;
    ABODY(kfB, vlB, vhB);
    if (t > NT) break;
  }
#undef ABODY
#undef LOADK
#undef LOADV

  // ---- normalize + store ctx
  u16* cp = Ctx + ((size_t)(bb * 2048) * 768) + hh * 64;
  float inv[16];
#pragma unroll
  for (int r = 0; r < 16; ++r) inv[r] = 1.0f / lacc[r];
#pragma unroll
  for (int r = 0; r < 16; ++r) {
    const int row = qw0 + (r & 3) + 8 * (r >> 2) + 4 * hi;
    cp[(size_t)row * 768 + l31]      = f2bf(oac0[r] * inv[r]);
    cp[(size_t)row * 768 + 32 + l31] = f2bf(oac1[r] * inv[r]);
  }
}

// ---------------------------------------------------------------- output GEMM
__global__ __launch_bounds__(256) void out_gemm(
    const u16* __restrict__ A, const u16* __restrict__ W,
    const float* __restrict__ bias, float* __restrict__ Out)
{
  __shared__ u16 At[2][64][64];
  __shared__ u16 Bt[2][64][64];
  const int lane = threadIdx.x & 63;
  const int w    = threadIdx.x >> 6;
  const int wr = w >> 1, wc = w & 1;
  const int mb = blockIdx.x * 64;
  const int nb = blockIdx.y * 64;

  const int lr = lane & 15;
  const int cl = lane >> 4;
  const int srow = lane >> 3;
  const int sx = (lane & 7) ^ srow;

  const f4 fz = {0.f, 0.f, 0.f, 0.f};
  f4 acc[2][2];
#pragma unroll
  for (int i = 0; i < 2; ++i)
#pragma unroll
    for (int j = 0; j < 2; ++j) acc[i][j] = fz;

  const u16* a0 = A + (size_t)mb * 768;
  const u16* b0 = W + (size_t)nb * 768;

#define OUT_STAGE(d, k0)                                                     \
  {                                                                          \
    const int r0 = w * 16;                                                   \
    gl_lds16(a0 + (size_t)(r0 + srow) * 768 + (k0) + sx * 8, &At[d][r0][0]); \
    gl_lds16(a0 + (size_t)(r0 + 8 + srow) * 768 + (k0) + sx * 8, &At[d][r0 + 8][0]); \
    gl_lds16(b0 + (size_t)(r0 + srow) * 768 + (k0) + sx * 8, &Bt[d][r0][0]); \
    gl_lds16(b0 + (size_t)(r0 + 8 + srow) * 768 + (k0) + sx * 8, &Bt[d][r0 + 8][0]); \
  }

  OUT_STAGE(0, 0);
  __syncthreads();
  int db = 0;
  for (int t = 0; t < 12; ++t) {
    if (t < 11) OUT_STAGE(db ^ 1, (t + 1) * 64);
#pragma unroll
    for (int h = 0; h < 2; ++h) {
      s8b af[2], bf[2];
#pragma unroll
      for (int i = 0; i < 2; ++i) {
        const int rr = wr * 32 + i * 16 + lr;
        af[i] = *(const s8b*)&At[db][rr][((h * 4 + cl) ^ (rr & 7)) * 8];
      }
#pragma unroll
      for (int j = 0; j < 2; ++j) {
        const int rr = wc * 32 + j * 16 + lr;
        bf[j] = *(const s8b*)&Bt[db][rr][((h * 4 + cl) ^ (rr & 7)) * 8];
      }
#pragma unroll
      for (int i = 0; i < 2; ++i)
#pragma unroll
        for (int j = 0; j < 2; ++j)
          acc[i][j] = __builtin_amdgcn_mfma_f32_16x16x32_bf16(af[i], bf[j], acc[i][j], 0, 0, 0);
    }
    __syncthreads();
    db ^= 1;
  }

  const int orow = cl * 4;
#pragma unroll
  for (int j = 0; j < 2; ++j) {
    const int n = nb + wc * 32 + j * 16 + lr;
    const float bn = bias[n];
#pragma unroll
    for (int i = 0; i < 2; ++i) {
      const int m0 = mb + wr * 32 + i * 16 + orow;
#pragma unroll
      for (int r = 0; r < 4; ++r)
        Out[(size_t)(m0 + r) * 768 + n] = acc[i][j][r] + bn;
    }
  }
}

// ---------------------------------------------------------------- launch
extern "C" void kernel_launch(void* const* d_in, const int* in_sizes, int n_in,
                              void* d_out, int out_size, void* d_ws, size_t ws_size,
                              hipStream_t stream) {
  const float* emb = (const float*)d_in[0];
  const float* Wq  = (const float*)d_in[1];
  const float* Wk  = (const float*)d_in[2];
  const float* Wv  = (const float*)d_in[3];
  const float* Wo  = (const float*)d_in[4];
  const float* bo  = (const float*)d_in[5];

  char* ws = (char*)d_ws;
  const size_t SZ_X = (size_t)4096 * 768 * 2;
  const size_t SZ_W = (size_t)768 * 768 * 2;
  u16* Wqb  = (u16*)(ws + SZ_X);
  u16* Wkb  = (u16*)(ws + SZ_X + SZ_W);
  u16* Wvb  = (u16*)(ws + SZ_X + 2 * SZ_W);
  u16* Wob  = (u16*)(ws + SZ_X + 3 * SZ_W);
  u16* Qfb  = (u16*)(ws + SZ_X + 4 * SZ_W);
  u16* Kfb  = (u16*)(ws + 2 * SZ_X + 4 * SZ_W);
  u16* Vfb  = (u16*)(ws + 3 * SZ_X + 4 * SZ_W);
  u16* Ctxb = (u16*)(ws + 4 * SZ_X + 4 * SZ_W);

  cvt_w<<<1024, 256, 0, stream>>>(Wq, Wk, Wv, Wo, Wqb, Wkb, Wvb, Wob);
  qkv_gemm<<<dim3(32, 8, 3), 256, 0, stream>>>(emb, Wqb, Wkb, Wvb, Qfb, Kfb, Vfb);
  attn_kernel<<<1536, 64, 0, stream>>>(Qfb, Kfb, Vfb, Ctxb);
  out_gemm<<<dim3(64, 12), 256, 0, stream>>>(Ctxb, Wob, bo, (float*)d_out);
}

// Round 12
// 89.606 us; speedup vs baseline: 1.4687x; 1.4687x over previous
//
#include <hip/hip_runtime.h>
#include <math.h>

typedef unsigned short u16;
typedef unsigned int u32;
typedef short s8b __attribute__((ext_vector_type(8)));     // 8 x bf16 (raw shorts)
typedef float f4 __attribute__((ext_vector_type(4)));
typedef float f16v __attribute__((ext_vector_type(16)));
typedef unsigned short u16x4 __attribute__((ext_vector_type(4)));
typedef unsigned int u32x4 __attribute__((ext_vector_type(4)));
typedef float f32x4 __attribute__((ext_vector_type(4)));

// fold 1/sqrt(64) * log2(e) into Q so softmax uses exp2 directly
#define SCALE_Q 0.18033688011112042f

__device__ __forceinline__ u16 f2bf(float f) {
  u32 u = __builtin_bit_cast(u32, f);
  u += 0x7fffu + ((u >> 16) & 1u);   // RNE
  return (u16)(u >> 16);
}

// async global->LDS, 16B per lane
__device__ __forceinline__ void gl_lds16(const u16* g, u16* l) {
  __builtin_amdgcn_global_load_lds(
      (const __attribute__((address_space(1))) u32*)g,
      (__attribute__((address_space(3))) u32*)l, 16, 0, 0);
}

__device__ __forceinline__ u32 cvtpk_bf16(float lo, float hi) {
  u32 r;
  asm volatile("v_cvt_pk_bf16_f32 %0, %1, %2" : "=v"(r) : "v"(lo), "v"(hi));
  return r;
}

__device__ __forceinline__ void plswap(u32& a, u32& b) {
  asm volatile("v_permlane32_swap_b32 %0, %1" : "+v"(a), "+v"(b));
}

// ---------------------------------------------------------------- convert
__global__ __launch_bounds__(256) void cvt_all(
    const float* __restrict__ e, const float* __restrict__ wq,
    const float* __restrict__ wk, const float* __restrict__ wv,
    const float* __restrict__ wo,
    u16* __restrict__ eo, u16* __restrict__ wqo, u16* __restrict__ wko,
    u16* __restrict__ wvo, u16* __restrict__ woo)
{
  const int EQ4 = 786432;
  const int WQ4 = 147456;
  const int TOT = EQ4 + 4 * WQ4;
  int i = blockIdx.x * 256 + threadIdx.x;
  const int stride = gridDim.x * 256;
  for (; i < TOT; i += stride) {
    const float* s; u16* d; int off;
    if (i < EQ4) { s = e; d = eo; off = i; }
    else {
      int j = i - EQ4; int w = j / WQ4; off = j - w * WQ4;
      s = (w == 0) ? wq : (w == 1) ? wk : (w == 2) ? wv : wo;
      d = (w == 0) ? wqo : (w == 1) ? wko : (w == 2) ? wvo : woo;
    }
    f32x4 v = ((const f32x4*)s)[off];
    u16x4 o = { f2bf(v[0]), f2bf(v[1]), f2bf(v[2]), f2bf(v[3]) };
    ((u16x4*)d)[off] = o;
  }
}

// ---------------------------------------------------------------- QKV GEMM
// 128x96 tile, BK=32, grid (32,8,3)=768 = 3 blocks/CU.
// Epilogues write FRAGMENT-MAJOR layouts consumed by attn:
//   Qf/Kf: [(b*12+h)*64 + g32][ks 0..3][lane 0..63][e 0..7]   (g32 = s>>5)
//   Vf   : [(b*12+h)*128 + g16][dhalf][lane][e]               (g16 = s>>4)
__global__ __launch_bounds__(256) void qkv_gemm(
    const u16* __restrict__ X, const u16* __restrict__ Wq,
    const u16* __restrict__ Wk, const u16* __restrict__ Wv,
    u16* __restrict__ Qf, u16* __restrict__ Kf, u16* __restrict__ Vf)
{
  __shared__ u16 At[2][128][32];
  __shared__ u16 Bt[2][96][32];
  const int lane = threadIdx.x & 63;
  const int w    = threadIdx.x >> 6;
  const int wr = w >> 1, wc = w & 1;
  const int mb = blockIdx.x * 128;
  const int nb = blockIdx.y * 96;
  const int z  = blockIdx.z;
  const u16* W = (z == 0) ? Wq : (z == 1) ? Wk : Wv;

  const int lr = lane & 15;
  const int cl = lane >> 4;             // k-chunk 0..3
  const int srow = lane >> 2;           // staging row 0..15
  const int sx = (lane & 3) ^ (srow & 3);

  const f4 fz = {0.f, 0.f, 0.f, 0.f};
  f4 acc[4][3];
#pragma unroll
  for (int i = 0; i < 4; ++i)
#pragma unroll
    for (int j = 0; j < 3; ++j) acc[i][j] = fz;

  const u16* a0 = X + (size_t)mb * 768;
  const u16* b0 = W + (size_t)nb * 768;

#define QKV_STAGE(d, k0)                                                       \
  {                                                                            \
    gl_lds16(a0 + (size_t)(w * 32 + srow) * 768 + (k0) + sx * 8,               \
             &At[d][w * 32][0]);                                               \
    gl_lds16(a0 + (size_t)(w * 32 + 16 + srow) * 768 + (k0) + sx * 8,          \
             &At[d][w * 32 + 16][0]);                                          \
    if (w < 3) {                                                               \
      gl_lds16(b0 + (size_t)(w * 32 + srow) * 768 + (k0) + sx * 8,             \
               &Bt[d][w * 32][0]);                                             \
      gl_lds16(b0 + (size_t)(w * 32 + 16 + srow) * 768 + (k0) + sx * 8,        \
               &Bt[d][w * 32 + 16][0]);                                        \
    }                                                                          \
  }

  QKV_STAGE(0, 0);
  __syncthreads();
  int db = 0;
  for (int t = 0; t < 24; ++t) {
    if (t < 23) QKV_STAGE(db ^ 1, (t + 1) * 32);
    s8b af[4], bf[3];
#pragma unroll
    for (int i = 0; i < 4; ++i) {
      const int rr = wr * 64 + i * 16 + lr;
      af[i] = *(const s8b*)&At[db][rr][(cl ^ (rr & 3)) * 8];
    }
#pragma unroll
    for (int j = 0; j < 3; ++j) {
      const int rr = wc * 48 + j * 16 + lr;
      bf[j] = *(const s8b*)&Bt[db][rr][(cl ^ (rr & 3)) * 8];
    }
#pragma unroll
    for (int i = 0; i < 4; ++i)
#pragma unroll
      for (int j = 0; j < 3; ++j)
        acc[i][j] = __builtin_amdgcn_mfma_f32_16x16x32_bf16(af[i], bf[j], acc[i][j], 0, 0, 0);
    __syncthreads();
    db ^= 1;
  }

  const int mbase = mb + wr * 64;
  const int nbase = nb + wc * 48;
  const int orow = cl * 4;
  if (z == 2) {
    // V fragment-major
#pragma unroll
    for (int i = 0; i < 4; ++i) {
      const int m0 = mbase + i * 16 + orow;   // kv token row
      const int b  = m0 >> 11, s0 = m0 & 2047;
      const int g16 = s0 >> 4, hi8 = (s0 >> 3) & 1, e0 = s0 & 7;
#pragma unroll
      for (int j = 0; j < 3; ++j) {
        const int n = nbase + j * 16 + lr;
        const int h = n >> 6, d6 = n & 63;
        const int dh = d6 >> 5, l31v = d6 & 31;
        u16x4 pk = { f2bf(acc[i][j][0]), f2bf(acc[i][j][1]),
                     f2bf(acc[i][j][2]), f2bf(acc[i][j][3]) };
        u16* dst = Vf + ((((size_t)(b * 12 + h) * 128 + g16) * 2 + dh) * 64
                         + hi8 * 32 + l31v) * 8 + e0;
        *(u16x4*)dst = pk;
      }
    }
  } else {
    // Q/K fragment-major
    u16* O = (z == 0) ? Qf : Kf;
    const float sc = (z == 0) ? SCALE_Q : 1.0f;
#pragma unroll
    for (int i = 0; i < 4; ++i) {
      const int m0 = mbase + i * 16 + orow;   // token row
      const int b  = m0 >> 11, s0 = m0 & 2047;
      const int g32 = s0 >> 5;
#pragma unroll
      for (int j = 0; j < 3; ++j) {
        const int n = nbase + j * 16 + lr;
        const int h = n >> 6, k6 = n & 63;
        const int ks = k6 >> 4, hi8 = (k6 >> 3) & 1, e = k6 & 7;
        u16* dst = O + ((((size_t)(b * 12 + h) * 64 + g32) * 4 + ks) * 64
                        + hi8 * 32) * 8 + e;
#pragma unroll
        for (int r = 0; r < 4; ++r)
          dst[(size_t)((s0 & 31) + r) * 8] = f2bf(acc[i][j][r] * sc);
      }
    }
  }
}

// ---------------------------------------------------------------- attention
// Best measured (45.7-46.3us): 1 wave per block, 32 q-rows, NO LDS, NO
// barriers. All loads fragment-major (base + lane*16, fully coalesced),
// software-pipelined one KV-tile ahead. Grid 1536, balanced heavy/light
// pairing. Deeper prefetch spills (r11); more waves don't help (r7).
__global__ __launch_bounds__(64, 2) void attn_kernel(
    const u16* __restrict__ Qf, const u16* __restrict__ Kf,
    const u16* __restrict__ Vf, u16* __restrict__ Ctx)
{
  const int lane = threadIdx.x;
  const int idx = blockIdx.x;
  const int half = (idx >= 768) ? 1 : 0;
  const int base = idx - half * 768;
  const int bh = base % 24;
  const int m  = base / 24;                 // 0..31
  const int qt32 = half ? (2 * m) : (63 - 2 * m);
  const int bb = bh / 12, hh = bh % 12;
  const int qw0 = qt32 * 32;
  const int l31 = lane & 31;
  const int hi  = lane >> 5;

  const u16* qfp = Qf + ((size_t)bh * 64 + qt32) * 4 * 512;   // 512 u16 per frag-block
  const u16* kfp = Kf + (size_t)bh * 64 * 4 * 512;
  const u16* vfp = Vf + (size_t)bh * 128 * 2 * 512;
  const int loff = lane * 8;

  s8b qf[4];
#pragma unroll
  for (int ks = 0; ks < 4; ++ks)
    qf[ks] = *(const s8b*)(qfp + ks * 512 + loff);

  s8b onesf;
#pragma unroll
  for (int i = 0; i < 8; ++i) onesf[i] = (short)0x3F80;   // bf16 1.0

  const f16v z16 = {0.f,0.f,0.f,0.f,0.f,0.f,0.f,0.f,
                    0.f,0.f,0.f,0.f,0.f,0.f,0.f,0.f};
  f16v oac0 = z16, oac1 = z16, lacc = z16;

  const int NT = qt32 >> 1;          // last kv-tile index
  const bool evenq = !(qt32 & 1);

  // ---- prologue: load K/V frags for tile 0
  s8b kf[8], vl[4], vh[4];
#pragma unroll
  for (int mt = 0; mt < 2; ++mt)
#pragma unroll
    for (int ks = 0; ks < 4; ++ks)
      kf[mt * 4 + ks] = *(const s8b*)(kfp + (mt * 4 + ks) * 512 + loff);
#pragma unroll
  for (int mt = 0; mt < 2; ++mt)
#pragma unroll
    for (int k2 = 0; k2 < 2; ++k2) {
      const int g16 = mt * 2 + k2;
      vl[mt * 2 + k2] = *(const s8b*)(vfp + (g16 * 2 + 0) * 512 + loff);
      vh[mt * 2 + k2] = *(const s8b*)(vfp + (g16 * 2 + 1) * 512 + loff);
    }

  for (int t = 0; t <= NT; ++t) {
    const bool last = (t == NT);
    const bool do1 = !(last && evenq);   // mt1 fully masked on even-q diag

    // ---- S^T = K * Q^T
    f16v st0 = z16, st1 = z16;
    __builtin_amdgcn_s_setprio(1);
#pragma unroll
    for (int ks = 0; ks < 4; ++ks)
      st0 = __builtin_amdgcn_mfma_f32_32x32x16_bf16(kf[ks], qf[ks], st0, 0, 0, 0);
    if (do1) {
#pragma unroll
      for (int ks = 0; ks < 4; ++ks)
        st1 = __builtin_amdgcn_mfma_f32_32x32x16_bf16(kf[4 + ks], qf[ks], st1, 0, 0, 0);
    }
    __builtin_amdgcn_s_setprio(0);

    // ---- prefetch K(t+1) (kf consumed above)
    if (!last) {
      const u16* kn = kfp + (size_t)(2 * t + 2) * 4 * 512;
#pragma unroll
      for (int mt = 0; mt < 2; ++mt)
#pragma unroll
        for (int ks = 0; ks < 4; ++ks)
          kf[mt * 4 + ks] = *(const s8b*)(kn + (mt * 4 + ks) * 512 + loff);
    }

    // ---- P = exp2(S'), causal mask on diagonal tile
    float p0[16], p1[16];
    if (last) {
      if (evenq) {
#pragma unroll
        for (int r = 0; r < 16; ++r) {
          const int crow = (r & 3) + 8 * (r >> 2) + 4 * hi;
          p0[r] = (crow <= l31) ? exp2f(st0[r]) : 0.f;
        }
      } else {
#pragma unroll
        for (int r = 0; r < 16; ++r) p0[r] = exp2f(st0[r]);
#pragma unroll
        for (int r = 0; r < 16; ++r) {
          const int crow = (r & 3) + 8 * (r >> 2) + 4 * hi;
          p1[r] = (crow <= l31) ? exp2f(st1[r]) : 0.f;
        }
      }
    } else {
#pragma unroll
      for (int r = 0; r < 16; ++r) p0[r] = exp2f(st0[r]);
#pragma unroll
      for (int r = 0; r < 16; ++r) p1[r] = exp2f(st1[r]);
    }

    // ---- pack P -> A-frags, PV + l MFMAs
#pragma unroll
    for (int mt = 0; mt < 2; ++mt) {
      if (mt == 1 && !do1) break;
      const float* pp = (mt == 0) ? p0 : p1;
      u32 pk0 = cvtpk_bf16(pp[0],  pp[1]);
      u32 pk1 = cvtpk_bf16(pp[2],  pp[3]);
      u32 pk2 = cvtpk_bf16(pp[4],  pp[5]);
      u32 pk3 = cvtpk_bf16(pp[6],  pp[7]);
      u32 pk4 = cvtpk_bf16(pp[8],  pp[9]);
      u32 pk5 = cvtpk_bf16(pp[10], pp[11]);
      u32 pk6 = cvtpk_bf16(pp[12], pp[13]);
      u32 pk7 = cvtpk_bf16(pp[14], pp[15]);
      plswap(pk0, pk2);
      plswap(pk1, pk3);
      plswap(pk4, pk6);
      plswap(pk5, pk7);
      u32x4 w0 = { pk0, pk1, pk2, pk3 };
      u32x4 w1 = { pk4, pk5, pk6, pk7 };
      s8b pa0 = __builtin_bit_cast(s8b, w0);
      s8b pa1 = __builtin_bit_cast(s8b, w1);
      __builtin_amdgcn_s_setprio(1);
      oac0 = __builtin_amdgcn_mfma_f32_32x32x16_bf16(pa0, vl[mt * 2 + 0], oac0, 0, 0, 0);
      oac0 = __builtin_amdgcn_mfma_f32_32x32x16_bf16(pa1, vl[mt * 2 + 1], oac0, 0, 0, 0);
      oac1 = __builtin_amdgcn_mfma_f32_32x32x16_bf16(pa0, vh[mt * 2 + 0], oac1, 0, 0, 0);
      oac1 = __builtin_amdgcn_mfma_f32_32x32x16_bf16(pa1, vh[mt * 2 + 1], oac1, 0, 0, 0);
      lacc = __builtin_amdgcn_mfma_f32_32x32x16_bf16(pa0, onesf, lacc, 0, 0, 0);
      lacc = __builtin_amdgcn_mfma_f32_32x32x16_bf16(pa1, onesf, lacc, 0, 0, 0);
      __builtin_amdgcn_s_setprio(0);
    }

    // ---- prefetch V(t+1) (vl/vh consumed above)
    if (!last) {
      const u16* vn = vfp + (size_t)(4 * t + 4) * 2 * 512;
#pragma unroll
      for (int mt = 0; mt < 2; ++mt)
#pragma unroll
        for (int k2 = 0; k2 < 2; ++k2) {
          const int g16 = mt * 2 + k2;
          vl[mt * 2 + k2] = *(const s8b*)(vn + (g16 * 2 + 0) * 512 + loff);
          vh[mt * 2 + k2] = *(const s8b*)(vn + (g16 * 2 + 1) * 512 + loff);
        }
    }
  }

  // ---- normalize + store ctx
  u16* cp = Ctx + ((size_t)(bb * 2048) * 768) + hh * 64;
  float inv[16];
#pragma unroll
  for (int r = 0; r < 16; ++r) inv[r] = 1.0f / lacc[r];
#pragma unroll
  for (int r = 0; r < 16; ++r) {
    const int row = qw0 + (r & 3) + 8 * (r >> 2) + 4 * hi;
    cp[(size_t)row * 768 + l31]      = f2bf(oac0[r] * inv[r]);
    cp[(size_t)row * 768 + 32 + l31] = f2bf(oac1[r] * inv[r]);
  }
}

// ---------------------------------------------------------------- output GEMM
__global__ __launch_bounds__(256) void out_gemm(
    const u16* __restrict__ A, const u16* __restrict__ W,
    const float* __restrict__ bias, float* __restrict__ Out)
{
  __shared__ u16 At[2][64][64];
  __shared__ u16 Bt[2][64][64];
  const int lane = threadIdx.x & 63;
  const int w    = threadIdx.x >> 6;
  const int wr = w >> 1, wc = w & 1;
  const int mb = blockIdx.x * 64;
  const int nb = blockIdx.y * 64;

  const int lr = lane & 15;
  const int cl = lane >> 4;
  const int srow = lane >> 3;
  const int sx = (lane & 7) ^ srow;

  const f4 fz = {0.f, 0.f, 0.f, 0.f};
  f4 acc[2][2];
#pragma unroll
  for (int i = 0; i < 2; ++i)
#pragma unroll
    for (int j = 0; j < 2; ++j) acc[i][j] = fz;

  const u16* a0 = A + (size_t)mb * 768;
  const u16* b0 = W + (size_t)nb * 768;

#define OUT_STAGE(d, k0)                                                     \
  {                                                                          \
    const int r0 = w * 16;                                                   \
    gl_lds16(a0 + (size_t)(r0 + srow) * 768 + (k0) + sx * 8, &At[d][r0][0]); \
    gl_lds16(a0 + (size_t)(r0 + 8 + srow) * 768 + (k0) + sx * 8, &At[d][r0 + 8][0]); \
    gl_lds16(b0 + (size_t)(r0 + srow) * 768 + (k0) + sx * 8, &Bt[d][r0][0]); \
    gl_lds16(b0 + (size_t)(r0 + 8 + srow) * 768 + (k0) + sx * 8, &Bt[d][r0 + 8][0]); \
  }

  OUT_STAGE(0, 0);
  __syncthreads();
  int db = 0;
  for (int t = 0; t < 12; ++t) {
    if (t < 11) OUT_STAGE(db ^ 1, (t + 1) * 64);
#pragma unroll
    for (int h = 0; h < 2; ++h) {
      s8b af[2], bf[2];
#pragma unroll
      for (int i = 0; i < 2; ++i) {
        const int rr = wr * 32 + i * 16 + lr;
        af[i] = *(const s8b*)&At[db][rr][((h * 4 + cl) ^ (rr & 7)) * 8];
      }
#pragma unroll
      for (int j = 0; j < 2; ++j) {
        const int rr = wc * 32 + j * 16 + lr;
        bf[j] = *(const s8b*)&Bt[db][rr][((h * 4 + cl) ^ (rr & 7)) * 8];
      }
#pragma unroll
      for (int i = 0; i < 2; ++i)
#pragma unroll
        for (int j = 0; j < 2; ++j)
          acc[i][j] = __builtin_amdgcn_mfma_f32_16x16x32_bf16(af[i], bf[j], acc[i][j], 0, 0, 0);
    }
    __syncthreads();
    db ^= 1;
  }

  const int orow = cl * 4;
#pragma unroll
  for (int j = 0; j < 2; ++j) {
    const int n = nb + wc * 32 + j * 16 + lr;
    const float bn = bias[n];
#pragma unroll
    for (int i = 0; i < 2; ++i) {
      const int m0 = mb + wr * 32 + i * 16 + orow;
#pragma unroll
      for (int r = 0; r < 4; ++r)
        Out[(size_t)(m0 + r) * 768 + n] = acc[i][j][r] + bn;
    }
  }
}

// ---------------------------------------------------------------- launch
extern "C" void kernel_launch(void* const* d_in, const int* in_sizes, int n_in,
                              void* d_out, int out_size, void* d_ws, size_t ws_size,
                              hipStream_t stream) {
  const float* emb = (const float*)d_in[0];
  const float* Wq  = (const float*)d_in[1];
  const float* Wk  = (const float*)d_in[2];
  const float* Wv  = (const float*)d_in[3];
  const float* Wo  = (const float*)d_in[4];
  const float* bo  = (const float*)d_in[5];

  char* ws = (char*)d_ws;
  const size_t SZ_X = (size_t)4096 * 768 * 2;
  const size_t SZ_W = (size_t)768 * 768 * 2;
  u16* Xb   = (u16*)(ws);
  u16* Wqb  = (u16*)(ws + SZ_X);
  u16* Wkb  = (u16*)(ws + SZ_X + SZ_W);
  u16* Wvb  = (u16*)(ws + SZ_X + 2 * SZ_W);
  u16* Wob  = (u16*)(ws + SZ_X + 3 * SZ_W);
  u16* Qfb  = (u16*)(ws + SZ_X + 4 * SZ_W);
  u16* Kfb  = (u16*)(ws + 2 * SZ_X + 4 * SZ_W);
  u16* Vfb  = (u16*)(ws + 3 * SZ_X + 4 * SZ_W);
  u16* Ctxb = (u16*)(ws + 4 * SZ_X + 4 * SZ_W);

  cvt_all<<<2048, 256, 0, stream>>>(emb, Wq, Wk, Wv, Wo, Xb, Wqb, Wkb, Wvb, Wob);
  qkv_gemm<<<dim3(32, 8, 3), 256, 0, stream>>>(Xb, Wqb, Wkb, Wvb, Qfb, Kfb, Vfb);
  attn_kernel<<<1536, 64, 0, stream>>>(Qfb, Kfb, Vfb, Ctxb);
  out_gemm<<<dim3(64, 12), 256, 0, stream>>>(Ctxb, Wob, bo, (float*)d_out);
}

// Round 13
// 89.587 us; speedup vs baseline: 1.4690x; 1.0002x over previous
//
#include <hip/hip_runtime.h>
#include <math.h>

typedef unsigned short u16;
typedef unsigned int u32;
typedef short s8b __attribute__((ext_vector_type(8)));     // 8 x bf16 (raw shorts)
typedef float f4 __attribute__((ext_vector_type(4)));
typedef float f16v __attribute__((ext_vector_type(16)));
typedef unsigned short u16x4 __attribute__((ext_vector_type(4)));
typedef unsigned int u32x4 __attribute__((ext_vector_type(4)));
typedef float f32x4 __attribute__((ext_vector_type(4)));

// fold 1/sqrt(64) * log2(e) into Q so softmax uses exp2 directly
#define SCALE_Q 0.18033688011112042f

__device__ __forceinline__ u16 f2bf(float f) {
  u32 u = __builtin_bit_cast(u32, f);
  u += 0x7fffu + ((u >> 16) & 1u);   // RNE
  return (u16)(u >> 16);
}

// async global->LDS, 16B per lane
__device__ __forceinline__ void gl_lds16(const u16* g, u16* l) {
  __builtin_amdgcn_global_load_lds(
      (const __attribute__((address_space(1))) u32*)g,
      (__attribute__((address_space(3))) u32*)l, 16, 0, 0);
}

__device__ __forceinline__ u32 cvtpk_bf16(float lo, float hi) {
  u32 r;
  asm volatile("v_cvt_pk_bf16_f32 %0, %1, %2" : "=v"(r) : "v"(lo), "v"(hi));
  return r;
}

__device__ __forceinline__ void plswap(u32& a, u32& b) {
  asm volatile("v_permlane32_swap_b32 %0, %1" : "+v"(a), "+v"(b));
}

// ---------------------------------------------------------------- convert
__global__ __launch_bounds__(256) void cvt_all(
    const float* __restrict__ e, const float* __restrict__ wq,
    const float* __restrict__ wk, const float* __restrict__ wv,
    const float* __restrict__ wo,
    u16* __restrict__ eo, u16* __restrict__ wqo, u16* __restrict__ wko,
    u16* __restrict__ wvo, u16* __restrict__ woo)
{
  const int EQ4 = 786432;
  const int WQ4 = 147456;
  const int TOT = EQ4 + 4 * WQ4;
  int i = blockIdx.x * 256 + threadIdx.x;
  const int stride = gridDim.x * 256;
  for (; i < TOT; i += stride) {
    const float* s; u16* d; int off;
    if (i < EQ4) { s = e; d = eo; off = i; }
    else {
      int j = i - EQ4; int w = j / WQ4; off = j - w * WQ4;
      s = (w == 0) ? wq : (w == 1) ? wk : (w == 2) ? wv : wo;
      d = (w == 0) ? wqo : (w == 1) ? wko : (w == 2) ? wvo : woo;
    }
    f32x4 v = ((const f32x4*)s)[off];
    u16x4 o = { f2bf(v[0]), f2bf(v[1]), f2bf(v[2]), f2bf(v[3]) };
    ((u16x4*)d)[off] = o;
  }
}

// ---------------------------------------------------------------- QKV GEMM
// 128x96 tile, BK=32, grid (32,8,3)=768 = 3 blocks/CU.
// Epilogues write FRAGMENT-MAJOR layouts consumed by attn:
//   Qf/Kf: [(b*12+h)*64 + g32][ks 0..3][lane 0..63][e 0..7]   (g32 = s>>5)
//   Vf   : [(b*12+h)*128 + g16][dhalf][lane][e]               (g16 = s>>4)
__global__ __launch_bounds__(256) void qkv_gemm(
    const u16* __restrict__ X, const u16* __restrict__ Wq,
    const u16* __restrict__ Wk, const u16* __restrict__ Wv,
    u16* __restrict__ Qf, u16* __restrict__ Kf, u16* __restrict__ Vf)
{
  __shared__ u16 At[2][128][32];
  __shared__ u16 Bt[2][96][32];
  const int lane = threadIdx.x & 63;
  const int w    = threadIdx.x >> 6;
  const int wr = w >> 1, wc = w & 1;
  const int mb = blockIdx.x * 128;
  const int nb = blockIdx.y * 96;
  const int z  = blockIdx.z;
  const u16* W = (z == 0) ? Wq : (z == 1) ? Wk : Wv;

  const int lr = lane & 15;
  const int cl = lane >> 4;             // k-chunk 0..3
  const int srow = lane >> 2;           // staging row 0..15
  const int sx = (lane & 3) ^ (srow & 3);

  const f4 fz = {0.f, 0.f, 0.f, 0.f};
  f4 acc[4][3];
#pragma unroll
  for (int i = 0; i < 4; ++i)
#pragma unroll
    for (int j = 0; j < 3; ++j) acc[i][j] = fz;

  const u16* a0 = X + (size_t)mb * 768;
  const u16* b0 = W + (size_t)nb * 768;

#define QKV_STAGE(d, k0)                                                       \
  {                                                                            \
    gl_lds16(a0 + (size_t)(w * 32 + srow) * 768 + (k0) + sx * 8,               \
             &At[d][w * 32][0]);                                               \
    gl_lds16(a0 + (size_t)(w * 32 + 16 + srow) * 768 + (k0) + sx * 8,          \
             &At[d][w * 32 + 16][0]);                                          \
    if (w < 3) {                                                               \
      gl_lds16(b0 + (size_t)(w * 32 + srow) * 768 + (k0) + sx * 8,             \
               &Bt[d][w * 32][0]);                                             \
      gl_lds16(b0 + (size_t)(w * 32 + 16 + srow) * 768 + (k0) + sx * 8,        \
               &Bt[d][w * 32 + 16][0]);                                        \
    }                                                                          \
  }

  QKV_STAGE(0, 0);
  __syncthreads();
  int db = 0;
  for (int t = 0; t < 24; ++t) {
    if (t < 23) QKV_STAGE(db ^ 1, (t + 1) * 32);
    s8b af[4], bf[3];
#pragma unroll
    for (int i = 0; i < 4; ++i) {
      const int rr = wr * 64 + i * 16 + lr;
      af[i] = *(const s8b*)&At[db][rr][(cl ^ (rr & 3)) * 8];
    }
#pragma unroll
    for (int j = 0; j < 3; ++j) {
      const int rr = wc * 48 + j * 16 + lr;
      bf[j] = *(const s8b*)&Bt[db][rr][(cl ^ (rr & 3)) * 8];
    }
#pragma unroll
    for (int i = 0; i < 4; ++i)
#pragma unroll
      for (int j = 0; j < 3; ++j)
        acc[i][j] = __builtin_amdgcn_mfma_f32_16x16x32_bf16(af[i], bf[j], acc[i][j], 0, 0, 0);
    __syncthreads();
    db ^= 1;
  }

  const int mbase = mb + wr * 64;
  const int nbase = nb + wc * 48;
  const int orow = cl * 4;
  if (z == 2) {
    // V fragment-major
#pragma unroll
    for (int i = 0; i < 4; ++i) {
      const int m0 = mbase + i * 16 + orow;   // kv token row
      const int b  = m0 >> 11, s0 = m0 & 2047;
      const int g16 = s0 >> 4, hi8 = (s0 >> 3) & 1, e0 = s0 & 7;
#pragma unroll
      for (int j = 0; j < 3; ++j) {
        const int n = nbase + j * 16 + lr;
        const int h = n >> 6, d6 = n & 63;
        const int dh = d6 >> 5, l31v = d6 & 31;
        u16x4 pk = { f2bf(acc[i][j][0]), f2bf(acc[i][j][1]),
                     f2bf(acc[i][j][2]), f2bf(acc[i][j][3]) };
        u16* dst = Vf + ((((size_t)(b * 12 + h) * 128 + g16) * 2 + dh) * 64
                         + hi8 * 32 + l31v) * 8 + e0;
        *(u16x4*)dst = pk;
      }
    }
  } else {
    // Q/K fragment-major
    u16* O = (z == 0) ? Qf : Kf;
    const float sc = (z == 0) ? SCALE_Q : 1.0f;
#pragma unroll
    for (int i = 0; i < 4; ++i) {
      const int m0 = mbase + i * 16 + orow;   // token row
      const int b  = m0 >> 11, s0 = m0 & 2047;
      const int g32 = s0 >> 5;
#pragma unroll
      for (int j = 0; j < 3; ++j) {
        const int n = nbase + j * 16 + lr;
        const int h = n >> 6, k6 = n & 63;
        const int ks = k6 >> 4, hi8 = (k6 >> 3) & 1, e = k6 & 7;
        u16* dst = O + ((((size_t)(b * 12 + h) * 64 + g32) * 4 + ks) * 64
                        + hi8 * 32) * 8 + e;
#pragma unroll
        for (int r = 0; r < 4; ++r)
          dst[(size_t)((s0 & 31) + r) * 8] = f2bf(acc[i][j][r] * sc);
      }
    }
  }
}

// ---------------------------------------------------------------- attention
// r12 structure + K-ONLY double buffer: kfA/kfB alternate; LOADK(t+1) is
// issued at the TOP of body t (into the set not used by QK(t)), giving the
// K loads a full body (~800-1000cyc) in flight instead of ~370. V stays
// single-buffered (its window is already ~500cyc). exp2/mask in place on
// st vectors (no p[] arrays) to stay under the 256-VGPR (64,2) cap.
__global__ __launch_bounds__(64, 2) void attn_kernel(
    const u16* __restrict__ Qf, const u16* __restrict__ Kf,
    const u16* __restrict__ Vf, u16* __restrict__ Ctx)
{
  const int lane = threadIdx.x;
  const int idx = blockIdx.x;
  const int half = (idx >= 768) ? 1 : 0;
  const int base = idx - half * 768;
  const int bh = base % 24;
  const int m  = base / 24;                 // 0..31
  const int qt32 = half ? (2 * m) : (63 - 2 * m);
  const int bb = bh / 12, hh = bh % 12;
  const int qw0 = qt32 * 32;
  const int l31 = lane & 31;
  const int hi  = lane >> 5;

  const u16* qfp = Qf + ((size_t)bh * 64 + qt32) * 4 * 512;   // 512 u16 per frag-block
  const u16* kfp = Kf + (size_t)bh * 64 * 4 * 512;
  const u16* vfp = Vf + (size_t)bh * 128 * 2 * 512;
  const int loff = lane * 8;

  s8b qf[4];
#pragma unroll
  for (int ks = 0; ks < 4; ++ks)
    qf[ks] = *(const s8b*)(qfp + ks * 512 + loff);

  s8b onesf;
#pragma unroll
  for (int i = 0; i < 8; ++i) onesf[i] = (short)0x3F80;   // bf16 1.0

  const f16v z16 = {0.f,0.f,0.f,0.f,0.f,0.f,0.f,0.f,
                    0.f,0.f,0.f,0.f,0.f,0.f,0.f,0.f};
  f16v oac0 = z16, oac1 = z16, lacc = z16;

  const int NT = qt32 >> 1;          // last kv-tile index
  const bool evenq = !(qt32 & 1);

  s8b kfA[8], kfB[8], vl[4], vh[4];

#define LOADK(DST, T)                                                          \
  {                                                                            \
    _Pragma("unroll")                                                          \
    for (int mt = 0; mt < 2; ++mt)                                             \
      _Pragma("unroll")                                                        \
      for (int ks = 0; ks < 4; ++ks)                                           \
        DST[mt * 4 + ks] =                                                     \
            *(const s8b*)(kfp + ((size_t)(2 * (T) + mt) * 4 + ks) * 512 + loff); \
  }
#define LOADV(T)                                                               \
  {                                                                            \
    _Pragma("unroll")                                                          \
    for (int mt = 0; mt < 2; ++mt)                                             \
      _Pragma("unroll")                                                        \
      for (int k2 = 0; k2 < 2; ++k2) {                                         \
        const int g16_ = 4 * (T) + 2 * mt + k2;                                \
        vl[mt * 2 + k2] = *(const s8b*)(vfp + ((size_t)g16_ * 2 + 0) * 512 + loff); \
        vh[mt * 2 + k2] = *(const s8b*)(vfp + ((size_t)g16_ * 2 + 1) * 512 + loff); \
      }                                                                        \
  }

// pack one P half (in PP, already exp'd/masked) and run its PV + l MFMAs
#define PVBLK(PP, MT)                                                          \
  {                                                                            \
    u32 pk0 = cvtpk_bf16(PP[0],  PP[1]);                                       \
    u32 pk1 = cvtpk_bf16(PP[2],  PP[3]);                                       \
    u32 pk2 = cvtpk_bf16(PP[4],  PP[5]);                                       \
    u32 pk3 = cvtpk_bf16(PP[6],  PP[7]);                                       \
    u32 pk4 = cvtpk_bf16(PP[8],  PP[9]);                                       \
    u32 pk5 = cvtpk_bf16(PP[10], PP[11]);                                      \
    u32 pk6 = cvtpk_bf16(PP[12], PP[13]);                                      \
    u32 pk7 = cvtpk_bf16(PP[14], PP[15]);                                      \
    plswap(pk0, pk2);                                                          \
    plswap(pk1, pk3);                                                          \
    plswap(pk4, pk6);                                                          \
    plswap(pk5, pk7);                                                          \
    u32x4 w0_ = { pk0, pk1, pk2, pk3 };                                        \
    u32x4 w1_ = { pk4, pk5, pk6, pk7 };                                        \
    s8b pa0 = __builtin_bit_cast(s8b, w0_);                                    \
    s8b pa1 = __builtin_bit_cast(s8b, w1_);                                    \
    __builtin_amdgcn_s_setprio(1);                                             \
    oac0 = __builtin_amdgcn_mfma_f32_32x32x16_bf16(pa0, vl[(MT) * 2 + 0], oac0, 0, 0, 0); \
    oac0 = __builtin_amdgcn_mfma_f32_32x32x16_bf16(pa1, vl[(MT) * 2 + 1], oac0, 0, 0, 0); \
    oac1 = __builtin_amdgcn_mfma_f32_32x32x16_bf16(pa0, vh[(MT) * 2 + 0], oac1, 0, 0, 0); \
    oac1 = __builtin_amdgcn_mfma_f32_32x32x16_bf16(pa1, vh[(MT) * 2 + 1], oac1, 0, 0, 0); \
    lacc = __builtin_amdgcn_mfma_f32_32x32x16_bf16(pa0, onesf, lacc, 0, 0, 0); \
    lacc = __builtin_amdgcn_mfma_f32_32x32x16_bf16(pa1, onesf, lacc, 0, 0, 0); \
    __builtin_amdgcn_s_setprio(0);                                             \
  }

#define ABODY(KC, KN)                                                          \
  {                                                                            \
    const bool last_ = (t == NT);                                              \
    const bool do1_ = !(last_ && evenq);                                       \
    if (!last_) LOADK(KN, t + 1);        /* top-of-body issue: full-body window */ \
    f16v st0 = z16, st1 = z16;                                                 \
    __builtin_amdgcn_s_setprio(1);                                             \
    _Pragma("unroll")                                                          \
    for (int ks = 0; ks < 4; ++ks)                                             \
      st0 = __builtin_amdgcn_mfma_f32_32x32x16_bf16(KC[ks], qf[ks], st0, 0, 0, 0); \
    if (do1_) {                                                                \
      _Pragma("unroll")                                                        \
      for (int ks = 0; ks < 4; ++ks)                                           \
        st1 = __builtin_amdgcn_mfma_f32_32x32x16_bf16(KC[4 + ks], qf[ks], st1, 0, 0, 0); \
    }                                                                          \
    __builtin_amdgcn_s_setprio(0);                                             \
    if (last_) {                                                               \
      if (evenq) {                                                             \
        _Pragma("unroll")                                                      \
        for (int r = 0; r < 16; ++r) {                                         \
          const int crow = (r & 3) + 8 * (r >> 2) + 4 * hi;                    \
          st0[r] = (crow <= l31) ? exp2f(st0[r]) : 0.f;                        \
        }                                                                      \
      } else {                                                                 \
        _Pragma("unroll")                                                      \
        for (int r = 0; r < 16; ++r) st0[r] = exp2f(st0[r]);                   \
        _Pragma("unroll")                                                      \
        for (int r = 0; r < 16; ++r) {                                         \
          const int crow = (r & 3) + 8 * (r >> 2) + 4 * hi;                    \
          st1[r] = (crow <= l31) ? exp2f(st1[r]) : 0.f;                        \
        }                                                                      \
      }                                                                        \
    } else {                                                                   \
      _Pragma("unroll")                                                        \
      for (int r = 0; r < 16; ++r) st0[r] = exp2f(st0[r]);                     \
      _Pragma("unroll")                                                        \
      for (int r = 0; r < 16; ++r) st1[r] = exp2f(st1[r]);                     \
    }                                                                          \
    PVBLK(st0, 0);                                                             \
    if (do1_) PVBLK(st1, 1);                                                   \
    if (!last_) LOADV(t + 1);                                                  \
    ++t;                                                                       \
  }

  LOADK(kfA, 0);
  LOADV(0);

  int t = 0;
  while (1) {
    ABODY(kfA, kfB);
    if (t > NT) break;
    ABODY(kfB, kfA);
    if (t > NT) break;
  }
#undef ABODY
#undef PVBLK
#undef LOADK
#undef LOADV

  // ---- normalize + store ctx
  u16* cp = Ctx + ((size_t)(bb * 2048) * 768) + hh * 64;
  float inv[16];
#pragma unroll
  for (int r = 0; r < 16; ++r) inv[r] = 1.0f / lacc[r];
#pragma unroll
  for (int r = 0; r < 16; ++r) {
    const int row = qw0 + (r & 3) + 8 * (r >> 2) + 4 * hi;
    cp[(size_t)row * 768 + l31]      = f2bf(oac0[r] * inv[r]);
    cp[(size_t)row * 768 + 32 + l31] = f2bf(oac1[r] * inv[r]);
  }
}

// ---------------------------------------------------------------- output GEMM
__global__ __launch_bounds__(256) void out_gemm(
    const u16* __restrict__ A, const u16* __restrict__ W,
    const float* __restrict__ bias, float* __restrict__ Out)
{
  __shared__ u16 At[2][64][64];
  __shared__ u16 Bt[2][64][64];
  const int lane = threadIdx.x & 63;
  const int w    = threadIdx.x >> 6;
  const int wr = w >> 1, wc = w & 1;
  const int mb = blockIdx.x * 64;
  const int nb = blockIdx.y * 64;

  const int lr = lane & 15;
  const int cl = lane >> 4;
  const int srow = lane >> 3;
  const int sx = (lane & 7) ^ srow;

  const f4 fz = {0.f, 0.f, 0.f, 0.f};
  f4 acc[2][2];
#pragma unroll
  for (int i = 0; i < 2; ++i)
#pragma unroll
    for (int j = 0; j < 2; ++j) acc[i][j] = fz;

  const u16* a0 = A + (size_t)mb * 768;
  const u16* b0 = W + (size_t)nb * 768;

#define OUT_STAGE(d, k0)                                                     \
  {                                                                          \
    const int r0 = w * 16;                                                   \
    gl_lds16(a0 + (size_t)(r0 + srow) * 768 + (k0) + sx * 8, &At[d][r0][0]); \
    gl_lds16(a0 + (size_t)(r0 + 8 + srow) * 768 + (k0) + sx * 8, &At[d][r0 + 8][0]); \
    gl_lds16(b0 + (size_t)(r0 + srow) * 768 + (k0) + sx * 8, &Bt[d][r0][0]); \
    gl_lds16(b0 + (size_t)(r0 + 8 + srow) * 768 + (k0) + sx * 8, &Bt[d][r0 + 8][0]); \
  }

  OUT_STAGE(0, 0);
  __syncthreads();
  int db = 0;
  for (int t = 0; t < 12; ++t) {
    if (t < 11) OUT_STAGE(db ^ 1, (t + 1) * 64);
#pragma unroll
    for (int h = 0; h < 2; ++h) {
      s8b af[2], bf[2];
#pragma unroll
      for (int i = 0; i < 2; ++i) {
        const int rr = wr * 32 + i * 16 + lr;
        af[i] = *(const s8b*)&At[db][rr][((h * 4 + cl) ^ (rr & 7)) * 8];
      }
#pragma unroll
      for (int j = 0; j < 2; ++j) {
        const int rr = wc * 32 + j * 16 + lr;
        bf[j] = *(const s8b*)&Bt[db][rr][((h * 4 + cl) ^ (rr & 7)) * 8];
      }
#pragma unroll
      for (int i = 0; i < 2; ++i)
#pragma unroll
        for (int j = 0; j < 2; ++j)
          acc[i][j] = __builtin_amdgcn_mfma_f32_16x16x32_bf16(af[i], bf[j], acc[i][j], 0, 0, 0);
    }
    __syncthreads();
    db ^= 1;
  }

  const int orow = cl * 4;
#pragma unroll
  for (int j = 0; j < 2; ++j) {
    const int n = nb + wc * 32 + j * 16 + lr;
    const float bn = bias[n];
#pragma unroll
    for (int i = 0; i < 2; ++i) {
      const int m0 = mb + wr * 32 + i * 16 + orow;
#pragma unroll
      for (int r = 0; r < 4; ++r)
        Out[(size_t)(m0 + r) * 768 + n] = acc[i][j][r] + bn;
    }
  }
}

// ---------------------------------------------------------------- launch
extern "C" void kernel_launch(void* const* d_in, const int* in_sizes, int n_in,
                              void* d_out, int out_size, void* d_ws, size_t ws_size,
                              hipStream_t stream) {
  const float* emb = (const float*)d_in[0];
  const float* Wq  = (const float*)d_in[1];
  const float* Wk  = (const float*)d_in[2];
  const float* Wv  = (const float*)d_in[3];
  const float* Wo  = (const float*)d_in[4];
  const float* bo  = (const float*)d_in[5];

  char* ws = (char*)d_ws;
  const size_t SZ_X = (size_t)4096 * 768 * 2;
  const size_t SZ_W = (size_t)768 * 768 * 2;
  u16* Xb   = (u16*)(ws);
  u16* Wqb  = (u16*)(ws + SZ_X);
  u16* Wkb  = (u16*)(ws + SZ_X + SZ_W);
  u16* Wvb  = (u16*)(ws + SZ_X + 2 * SZ_W);
  u16* Wob  = (u16*)(ws + SZ_X + 3 * SZ_W);
  u16* Qfb  = (u16*)(ws + SZ_X + 4 * SZ_W);
  u16* Kfb  = (u16*)(ws + 2 * SZ_X + 4 * SZ_W);
  u16* Vfb  = (u16*)(ws + 3 * SZ_X + 4 * SZ_W);
  u16* Ctxb = (u16*)(ws + 4 * SZ_X + 4 * SZ_W);

  cvt_all<<<2048, 256, 0, stream>>>(emb, Wq, Wk, Wv, Wo, Xb, Wqb, Wkb, Wvb, Wob);
  qkv_gemm<<<dim3(32, 8, 3), 256, 0, stream>>>(Xb, Wqb, Wkb, Wvb, Qfb, Kfb, Vfb);
  attn_kernel<<<1536, 64, 0, stream>>>(Qfb, Kfb, Vfb, Ctxb);
  out_gemm<<<dim3(64, 12), 256, 0, stream>>>(Ctxb, Wob, bo, (float*)d_out);
}